// Round 1
// baseline (181.153 us; speedup 1.0000x reference)
//
#include <hip/hip_runtime.h>
#include <stdint.h>

// Problem constants
#define BATCH 16384
#define INDIM 256
#define DDIM  128
#define NEXP  8
#define ROWS  64          // batch rows per block: 2 row-groups x (2 row-tiles of 16)
#define THREADS 512       // 8 waves = 2 row-groups x 4 col-groups
#define NSTEP 192         // flattened g = st*64 + eb*8 + kt
#define RINGD 8           // LDS staging ring depth (slabs of 8KB)

typedef __bf16 bfv8  __attribute__((ext_vector_type(8)));   // MFMA A/B frag: 8 bf16 = 4 VGPRs
typedef float  f32x4 __attribute__((ext_vector_type(4)));   // MFMA C/D frag

typedef __attribute__((address_space(1))) const void gas_void;
typedef __attribute__((address_space(3))) void las_void;

// ---------------------------------------------------------------------------
// Prep kernel (unchanged): repack Wa/Wb/Ws and Gcat into bf16 MFMA B-fragment
// layout. W frag for flattened g = st*64+e*8+kt lives at wp + g*4096 elems;
// within a slab: nt*512 + lane*8, elem j = W[i][d], i = kt*32+(lane>>4)*8+j,
// d = nt*16+(lane&15).
// ---------------------------------------------------------------------------
__global__ void prep_kernel(const float* __restrict__ Wa, const float* __restrict__ Wb,
                            const float* __restrict__ Ws, const float* __restrict__ Ga,
                            const float* __restrict__ Gb, const float* __restrict__ Gs,
                            __bf16* __restrict__ wp, __bf16* __restrict__ gp) {
    int t = blockIdx.x * 256 + threadIdx.x;
    const int NW = 3 * 8 * 8 * 8 * 64;   // 98304 W-frag slots
    if (t < NW) {
        int lane = t & 63, nt = (t >> 6) & 7, kt = (t >> 9) & 7, e = (t >> 12) & 7, st = t >> 15;
        const float* W = (st == 0) ? Wa : (st == 1) ? Wb : Ws;
        int d  = nt * 16 + (lane & 15);
        int i0 = kt * 32 + (lane >> 4) * 8;
        __bf16* o = wp + (size_t)t * 8;
#pragma unroll
        for (int j = 0; j < 8; j++)
            o[j] = (__bf16)W[(size_t)(e * 256 + i0 + j) * 128 + d];
    } else if (t < NW + 2048) {
        int t2 = t - NW;
        int lane = t2 & 63, nt = (t2 >> 6) & 3, kt = t2 >> 8;
        int g  = nt * 16 + (lane & 15);
        int k0 = kt * 32 + (lane >> 4) * 8;
        __bf16* o = gp + (size_t)t2 * 8;
#pragma unroll
        for (int j = 0; j < 8; j++) {
            int k = k0 + j;
            float v = 0.f;
            if (g < 16)      v = Ga[g * 256 + k];
            else if (g < 32) v = Gb[(g - 16) * 256 + k];
            else if (g < 56) v = Gs[(g - 32) * 256 + k];
            o[j] = (__bf16)v;
        }
    }
}

// Load A fragments (2 row-tiles x 8 k-tiles), fp32->bf16, NONTEMPORAL so the
// x streams don't evict the weight working set from L2.
__device__ __forceinline__ void load_afr(const float* __restrict__ x, int rb,
                                         int l16, int quad, bfv8 afr[2][8]) {
#pragma unroll
    for (int mt = 0; mt < 2; mt++) {
        const float* xr = x + (size_t)(rb + mt * 16 + l16) * INDIM;
#pragma unroll
        for (int kt = 0; kt < 8; kt++) {
            const f32x4* p = (const f32x4*)(xr + kt * 32 + quad * 8);
            f32x4 lo = __builtin_nontemporal_load(p);
            f32x4 hi = __builtin_nontemporal_load(p + 1);
            bfv8 a;
            a[0] = (__bf16)lo[0]; a[1] = (__bf16)lo[1]; a[2] = (__bf16)lo[2]; a[3] = (__bf16)lo[3];
            a[4] = (__bf16)hi[0]; a[5] = (__bf16)hi[1]; a[6] = (__bf16)hi[2]; a[7] = (__bf16)hi[3];
            afr[mt][kt] = a;
        }
    }
}

// Stage one step's 8KB fragment slab into the LDS ring via global_load_lds.
// LDS dest is wave-uniform base + lane*16 (HW-defined); wave wv covers slab
// elems [wv*512, wv*512+512). Global src is per-lane. Counts in vmcnt.
__device__ __forceinline__ void stage_step(const __bf16* __restrict__ wp,
                                           __bf16* ring, int g, int wv, int lane) {
    const __bf16* src = wp + ((size_t)g << 12) + (wv << 9) + (lane << 3);
    __bf16* dst = ring + ((size_t)(g & (RINGD - 1)) << 12) + (wv << 9);
    __builtin_amdgcn_global_load_lds((gas_void*)src, (las_void*)dst, 16, 0, 0);
}

// ---------------------------------------------------------------------------
// Main fused kernel. Grid 256 blocks (1/CU) x 512 threads (8 waves).
// Block owns 64 batch rows. Wave (rg,cg): rows [rg*32, rg*32+32) of the block,
// output cols [cg*32, cg*32+32). R5: B fragments staged ONCE per block into a
// depth-8 LDS ring via global_load_lds (8KB/step), consumed by all waves.
// Pipeline invariants per step g:
//   [s_waitcnt vmcnt(6)]  -> retires own stage(g) (7 glls outstanding max)
//   [s_barrier]           -> all waves' stage(g) retired; step g-1 reads done
//   [issue stage(g+7)]    -> targets slot (g-1)&7, safe to overwrite (WAR ok)
//   [ds_read slot g&7 + 4 MFMA]
// Weight traffic: 256 blocks x 1.5MB = 384MB, each fragment fetched once per
// block (vs 768MB per-wave fetch at ROWS=32).
// ---------------------------------------------------------------------------
__launch_bounds__(THREADS, 2)
__global__ void ple_kernel(const float* __restrict__ xa, const float* __restrict__ xb,
                           const float* __restrict__ xs,
                           const float* __restrict__ ba, const float* __restrict__ bb,
                           const float* __restrict__ bs,
                           const __bf16* __restrict__ wp, const __bf16* __restrict__ gp,
                           float* __restrict__ out) {
    __shared__ __bf16 ring[RINGD * 4096];   // 64 KB staging ring
    __shared__ float lgt[ROWS * 64];        // 16 KB logits [row][gate]
    __shared__ float wT[64 * ROWS];         // 16 KB softmax weights [gate][row]

    const int tid  = threadIdx.x;
    const int wv   = tid >> 6;        // wave id 0..7
    const int lane = tid & 63;
    const int rg   = wv >> 2;         // row-group 0..1
    const int cg   = wv & 3;          // col-group 0..3
    const int quad = lane >> 4;
    const int l16  = lane & 15;
    const int r0   = blockIdx.x * ROWS;
    const int rb   = r0 + rg * 32;    // this wave's row base

    // Prologue: prime ring with steps 0..6. Latency hides under phase 1
    // (phase 1's __syncthreads fully drains vmcnt, so first loop waits are free).
#pragma unroll
    for (int i = 0; i < RINGD - 1; i++) stage_step(wp, ring, i, wv, lane);

    bfv8 afr[2][8];                   // A frags: 2 row-tiles x 8 k-tiles (64 VGPRs)

    // ---------------- Phase 1: gate logits via MFMA ----------------
    {
        const float* x = (cg == 0) ? xa : (cg == 1) ? xb : xs;  // wave-uniform
        load_afr(x, rb, l16, quad, afr);
        f32x4 acc1[2];
#pragma unroll
        for (int mt = 0; mt < 2; mt++) { f32x4 z = {0.f, 0.f, 0.f, 0.f}; acc1[mt] = z; }
#pragma unroll
        for (int kt = 0; kt < 8; kt++) {
            bfv8 gfr = *(const bfv8*)(gp + ((size_t)(kt * 4 + cg) * 64 + lane) * 8);
#pragma unroll
            for (int mt = 0; mt < 2; mt++)
                acc1[mt] = __builtin_amdgcn_mfma_f32_16x16x32_bf16(afr[mt][kt], gfr, acc1[mt], 0, 0, 0);
        }
#pragma unroll
        for (int mt = 0; mt < 2; mt++)
#pragma unroll
            for (int r = 0; r < 4; r++)
                lgt[(rg * 32 + mt * 16 + quad * 4 + r) * 64 + cg * 16 + l16] = acc1[mt][r];
    }
    __syncthreads();

    // ---------------- softmax per row (64 rows, one wave) ----------------
    if (tid < ROWS) {
        const float* L = lgt + tid * 64;
#pragma unroll
        for (int gi = 0; gi < 3; gi++) {
            const int base = (gi == 0) ? 0 : (gi == 1 ? 16 : 32);
            const int cnt  = (gi == 2) ? 24 : 16;
            float m = -1e30f;
            for (int k = 0; k < cnt; k++) m = fmaxf(m, L[base + k]);
            float s = 0.f;
            for (int k = 0; k < cnt; k++) s += __expf(L[base + k] - m);
            float inv = 1.f / s;
            for (int k = 0; k < cnt; k++) wT[(base + k) * ROWS + tid] = __expf(L[base + k] - m) * inv;
        }
    }
    __syncthreads();

    // ---------------- Phase 2: experts + gated accumulation ----------------
    float o[3][2][2][4];
#pragma unroll
    for (int oi = 0; oi < 3; oi++)
#pragma unroll
        for (int mt = 0; mt < 2; mt++)
#pragma unroll
            for (int ntl = 0; ntl < 2; ntl++)
#pragma unroll
                for (int r = 0; r < 4; r++) o[oi][mt][ntl][r] = 0.f;

#define FOLD(oi, gbase)                                                                 \
    {                                                                                   \
        _Pragma("unroll")                                                               \
        for (int mt = 0; mt < 2; mt++) {                                                \
            f32x4 wv4 = *(const f32x4*)(wT + (gbase + eb) * ROWS + rg * 32 + mt * 16 + quad * 4); \
            _Pragma("unroll")                                                           \
            for (int ntl = 0; ntl < 2; ntl++)                                           \
                _Pragma("unroll")                                                       \
                for (int r = 0; r < 4; r++)                                             \
                    o[oi][mt][ntl][r] += wv4[r] * acc[mt][ntl][r];                      \
        }                                                                               \
    }

#pragma unroll
    for (int st = 0; st < 3; st++) {
        const float* x    = (st == 0) ? xa : (st == 1) ? xb : xs;
        const float* bias = (st == 0) ? ba : (st == 1) ? bb : bs;
        load_afr(x, rb, l16, quad, afr);

#pragma unroll 1
        for (int eb = 0; eb < NEXP; eb++) {
            float b0 = bias[eb * 128 + cg * 32 + l16];
            float b1 = bias[eb * 128 + cg * 32 + 16 + l16];

            f32x4 acc[2][2];
#pragma unroll
            for (int mt = 0; mt < 2; mt++)
#pragma unroll
                for (int ntl = 0; ntl < 2; ntl++) { f32x4 z = {0.f, 0.f, 0.f, 0.f}; acc[mt][ntl] = z; }

#pragma unroll
            for (int kt = 0; kt < 8; kt++) {
                const int g  = st * 64 + eb * 8 + kt;
                const int rem = NSTEP - 1 - g;    // outstanding-1 in tail
                // Counted wait (never a drain in steady state): retires stage(g).
                // Folds to vmcnt(6) for st<2; the tail chain only materializes
                // in the final expert of st=2.
                if (rem >= 6)      asm volatile("s_waitcnt vmcnt(6)" ::: "memory");
                else if (rem == 5) asm volatile("s_waitcnt vmcnt(5)" ::: "memory");
                else if (rem == 4) asm volatile("s_waitcnt vmcnt(4)" ::: "memory");
                else if (rem == 3) asm volatile("s_waitcnt vmcnt(3)" ::: "memory");
                else if (rem == 2) asm volatile("s_waitcnt vmcnt(2)" ::: "memory");
                else if (rem == 1) asm volatile("s_waitcnt vmcnt(1)" ::: "memory");
                else               asm volatile("s_waitcnt vmcnt(0)" ::: "memory");
                __builtin_amdgcn_s_barrier();
                asm volatile("" ::: "memory");          // IR fence: no ds_read hoists above barrier
                __builtin_amdgcn_sched_barrier(0);      // MIR fence (rule #18 analog)
                if (g + RINGD - 1 < NSTEP)
                    stage_step(wp, ring, g + RINGD - 1, wv, lane);   // overwrites slot (g-1)&7: WAR-safe

                const __bf16* slab = ring + ((size_t)(g & (RINGD - 1)) << 12) + (cg << 10);
                bfv8 bv0 = *(const bfv8*)(slab + ((size_t)lane << 3));
                bfv8 bv1 = *(const bfv8*)(slab + 512 + ((size_t)lane << 3));
                acc[0][0] = __builtin_amdgcn_mfma_f32_16x16x32_bf16(afr[0][kt], bv0, acc[0][0], 0, 0, 0);
                acc[1][0] = __builtin_amdgcn_mfma_f32_16x16x32_bf16(afr[1][kt], bv0, acc[1][0], 0, 0, 0);
                acc[0][1] = __builtin_amdgcn_mfma_f32_16x16x32_bf16(afr[0][kt], bv1, acc[0][1], 0, 0, 0);
                acc[1][1] = __builtin_amdgcn_mfma_f32_16x16x32_bf16(afr[1][kt], bv1, acc[1][1], 0, 0, 0);
            }

            // bias (per output column)
#pragma unroll
            for (int mt = 0; mt < 2; mt++)
#pragma unroll
                for (int r = 0; r < 4; r++) { acc[mt][0][r] += b0; acc[mt][1][r] += b1; }

            // gated fold. Gate table columns: a:0-15, b:16-31, s:32-55.
            if (st == 0)      { FOLD(0, 0);  FOLD(2, 32); }
            else if (st == 1) { FOLD(1, 16); FOLD(2, 40); }
            else              { FOLD(0, 8);  FOLD(1, 24); FOLD(2, 48); }
        }
    }
#undef FOLD

    // ---------------- epilogue: store 3 outputs (nontemporal) ----------------
#pragma unroll
    for (int oi = 0; oi < 3; oi++) {
        float* ob = out + (size_t)oi * BATCH * DDIM;
#pragma unroll
        for (int mt = 0; mt < 2; mt++)
#pragma unroll
            for (int r = 0; r < 4; r++) {
                int row = rb + mt * 16 + quad * 4 + r;
#pragma unroll
                for (int ntl = 0; ntl < 2; ntl++)
                    __builtin_nontemporal_store(o[oi][mt][ntl][r],
                        &ob[(size_t)row * DDIM + cg * 32 + ntl * 16 + l16]);
            }
    }
}

extern "C" void kernel_launch(void* const* d_in, const int* in_sizes, int n_in,
                              void* d_out, int out_size, void* d_ws, size_t ws_size,
                              hipStream_t stream) {
    const float* xa = (const float*)d_in[0];
    const float* xb = (const float*)d_in[1];
    const float* xs = (const float*)d_in[2];
    const float* Wa = (const float*)d_in[3];
    const float* ba = (const float*)d_in[4];
    const float* Wb = (const float*)d_in[5];
    const float* bb = (const float*)d_in[6];
    const float* Ws = (const float*)d_in[7];
    const float* bs = (const float*)d_in[8];
    const float* Ga = (const float*)d_in[9];
    const float* Gb = (const float*)d_in[10];
    const float* Gs = (const float*)d_in[11];

    __bf16* wp = (__bf16*)d_ws;                 // 1.5 MB packed expert weights
    __bf16* gp = wp + 3 * 8 * 8 * 8 * 64 * 8;   // 32 KB packed gate matrix

    prep_kernel<<<392, 256, 0, stream>>>(Wa, Wb, Ws, Ga, Gb, Gs, wp, gp);
    ple_kernel<<<BATCH / ROWS, THREADS, 0, stream>>>(xa, xb, xs, ba, bb, bs, wp, gp, (float*)d_out);
}